// Round 11
// baseline (96.865 us; speedup 1.0000x reference)
//
#include <hip/hip_runtime.h>
#include <hip/hip_bf16.h>

#define NROWS 8192      // B*T
#define KDIM  768       // F_IN
#define VSZ   320       // V
#define GSZ   2         // G
#define NCOL  640       // G*V
#define DSZ   128       // D
#define BM    32        // rows per block
#define NMT   (NROWS / BM)             // 256 M-tiles
#define NBLK  (NMT * 2)                // 512 blocks (x2 group-halves)
#define NKB   24                       // K blocks of 32
#define KHALF 12                       // K blocks per K-half
#define XQ_TOTAL (NROWS * GSZ * DSZ)   // 2097152
#define MARGIN 1.5f
#define XBLKS 3072                     // prep blocks for x
#define WBLKS 240                      // prep blocks for W

typedef __attribute__((ext_vector_type(8))) short bf16x8;
typedef __attribute__((ext_vector_type(4))) float f32x4;
typedef __attribute__((ext_vector_type(4))) int   i32x4;

static __device__ __forceinline__ short f2bf(float f) {
    union { __hip_bfloat16 h; short s; } u;
    u.h = __float2bfloat16(f);   // round-to-nearest-even
    return u.s;
}

// ---------------- prep: pack x and W to frag-major bf16; zero accf ----------------
__global__ __launch_bounds__(256) void prep_k(const float* __restrict__ x,
                                              const float* __restrict__ W,
                                              short* __restrict__ Xb,
                                              short* __restrict__ Wb,
                                              float* __restrict__ accf) {
    const int bid = blockIdx.x;
    if (bid == 0) {
        for (int i = threadIdx.x; i < 2 * NCOL; i += 256) accf[i] = 0.f;
    }
    const float* src;
    short* dst;
    int id, row, k;
    if (bid < XBLKS) {
        id = bid * 256 + threadIdx.x;           // 0..786431
        const int lane = id & 63;
        const int f    = id >> 6;               // 0..12287
        const int rblk = f / NKB;
        const int kb   = f - rblk * NKB;
        row = rblk * 16 + (lane & 15);
        k   = kb * 32 + (lane >> 4) * 8;
        src = x; dst = Xb;
    } else {
        id = (bid - XBLKS) * 256 + threadIdx.x; // 0..61439
        const int lane = id & 63;
        const int f    = id >> 6;               // 0..959
        const int n    = f % 5;
        const int t2   = f / 5;
        const int hc   = t2 & 7;
        const int kb   = t2 >> 3;               // 0..23
        row = (hc * 5 + n) * 16 + (lane & 15);  // W col
        k   = kb * 32 + (lane >> 4) * 8;
        src = W; dst = Wb;
    }
    const float4 a = *(const float4*)(src + (size_t)row * KDIM + k);
    const float4 c = *(const float4*)(src + (size_t)row * KDIM + k + 4);
    bf16x8 r;
    r[0] = f2bf(a.x); r[1] = f2bf(a.y); r[2] = f2bf(a.z); r[3] = f2bf(a.w);
    r[4] = f2bf(c.x); r[5] = f2bf(c.y); r[6] = f2bf(c.z); r[7] = f2bf(c.w);
    *(bf16x8*)(dst + (size_t)id * 8) = r;
}

// ---------------- fused: split-K MFMA GEMM + argmax + softmax + refine + gather ----------------
// (identical to round 10 — current best; kept as the production path)
__global__ __launch_bounds__(1024, 8) void fused_vq_k(
    const short* __restrict__ Xb, const short* __restrict__ Wb,
    const float* __restrict__ x, const float* __restrict__ W,
    const float* __restrict__ b, const float* __restrict__ codebook,
    float* __restrict__ accf, float* __restrict__ xq) {

    __shared__ f32x4 comb[2][4][5][64];   // 40,960 B: kh=1 partial acc
    __shared__ float pacc[2][VSZ];
    __shared__ float cnt_f[VSZ];
    __shared__ float wmax[BM][4];
    __shared__ int   warg[BM][4];
    __shared__ float ssum[BM][4];
    __shared__ float rmax_s[BM];
    __shared__ int   rarg_s[BM];
    __shared__ int   cnt_s[BM];
    __shared__ int   list_s[BM][16];
    __shared__ int   code_s[BM];
    __shared__ int   work_s[BM];
    __shared__ int   nwork_s;

    const int tid   = threadIdx.x;
    const int lane  = tid & 63;
    const int w     = tid >> 6;       // wave 0..15
    const int l15   = lane & 15;
    const int l4    = lane >> 4;      // 0..3
    const int sb    = ((int)blockIdx.x & 7) * (NBLK / 8) + ((int)blockIdx.x >> 3);
    const int mt    = sb >> 1;
    const int h     = sb & 1;         // group
    const int row0  = mt * BM;
    const int kh    = w >> 3;         // K-half 0..1
    const int rs    = (w >> 2) & 1;   // row-set 0..1 (16 rows)
    const int cc    = w & 3;          // col-chunk 0..3 (80 cols)
    const int rbase = rs * 16;
    const int hc    = h * 4 + cc;
    const int nf0   = hc * 5;         // first 16-col frag (global)

    for (int i = tid; i < VSZ; i += 1024) cnt_f[i] = 0.f;
    if (tid < BM) cnt_s[tid] = 0;
    if (tid == 0) nwork_s = 0;

    const short* Ap = Xb + ((size_t)(mt * 2 + rs) * NKB) * 512 + (size_t)lane * 8;
    const short* Bp = Wb + ((size_t)hc * 5) * 512 + (size_t)lane * 8;

    f32x4 acc[5];
#pragma unroll
    for (int n = 0; n < 5; ++n) acc[n] = (f32x4){0.f, 0.f, 0.f, 0.f};

#pragma unroll 1
    for (int kb2 = 0; kb2 < KHALF; ++kb2) {
        const int kb = kh * KHALF + kb2;
        const bf16x8 a_ = *(const bf16x8*)(Ap + (size_t)kb * 512);
        bf16x8 bf[5];
#pragma unroll
        for (int n = 0; n < 5; ++n)
            bf[n] = *(const bf16x8*)(Bp + (size_t)kb * (8 * 5 * 512) + n * 512);
#pragma unroll
        for (int n = 0; n < 5; ++n)
            acc[n] = __builtin_amdgcn_mfma_f32_16x16x32_bf16(a_, bf[n], acc[n], 0, 0, 0);
    }

    if (kh == 1) {
#pragma unroll
        for (int n = 0; n < 5; ++n) comb[rs][cc][n][lane] = acc[n];
    }
    __syncthreads();
    if (kh == 0) {
#pragma unroll
        for (int n = 0; n < 5; ++n) {
            const f32x4 o = comb[rs][cc][n][lane];
#pragma unroll
            for (int r = 0; r < 4; ++r) acc[n][r] += o[r];
        }
#pragma unroll
        for (int n = 0; n < 5; ++n) {
            const float bv = b[(nf0 + n) * 16 + l15];
#pragma unroll
            for (int r = 0; r < 4; ++r) acc[n][r] += bv;
        }
        float m4[4]; int a4[4];
#pragma unroll
        for (int r = 0; r < 4; ++r) { m4[r] = -3.4e38f; a4[r] = 0x7fffffff; }
#pragma unroll
        for (int n = 0; n < 5; ++n) {
            const int col = (nf0 + n) * 16 + l15;
#pragma unroll
            for (int r = 0; r < 4; ++r) {
                const float v = acc[n][r];
                if (v > m4[r]) { m4[r] = v; a4[r] = col; }
            }
        }
#pragma unroll
        for (int off = 8; off >= 1; off >>= 1)
#pragma unroll
            for (int r = 0; r < 4; ++r) {
                const float om = __shfl_xor(m4[r], off);
                const int   oa = __shfl_xor(a4[r], off);
                if (om > m4[r] || (om == m4[r] && oa < a4[r])) { m4[r] = om; a4[r] = oa; }
            }
        if (l15 == 0)
#pragma unroll
            for (int r = 0; r < 4; ++r) {
                const int row = rbase + l4 * 4 + r;
                wmax[row][cc] = m4[r];
                warg[row][cc] = a4[r];
            }
    }
    __syncthreads();

    if (tid < BM) {
        float m = -3.4e38f; int c = 0x7fffffff;
#pragma unroll
        for (int q = 0; q < 4; ++q) {
            const float mq = wmax[tid][q];
            const int   cq = warg[tid][q];
            if (mq > m || (mq == m && cq < c)) { m = mq; c = cq; }
        }
        rmax_s[tid] = m;
        rarg_s[tid] = c;
    }
    __syncthreads();

    if (kh == 0) {
        float rm[4];
#pragma unroll
        for (int r = 0; r < 4; ++r) rm[r] = rmax_s[rbase + l4 * 4 + r];
        float sden[4] = {0.f, 0.f, 0.f, 0.f};
#pragma unroll
        for (int n = 0; n < 5; ++n) {
            const int col = (nf0 + n) * 16 + l15;
#pragma unroll
            for (int r = 0; r < 4; ++r) {
                const float v = acc[n][r];
                if (v > rm[r] - MARGIN) {
                    const int row = rbase + l4 * 4 + r;
                    const int idx = atomicAdd(&cnt_s[row], 1);
                    if (idx < 16) list_s[row][idx] = col;
                }
                const float e = __expf(v - rm[r]);
                acc[n][r] = e;
                sden[r] += e;
            }
        }
#pragma unroll
        for (int off = 8; off >= 1; off >>= 1)
#pragma unroll
            for (int r = 0; r < 4; ++r) sden[r] += __shfl_xor(sden[r], off);
        if (l15 == 0)
#pragma unroll
            for (int r = 0; r < 4; ++r) ssum[rbase + l4 * 4 + r][cc] = sden[r];
    }
    __syncthreads();

    if (tid < BM) {
        if (cnt_s[tid] <= 1) {
            code_s[tid] = rarg_s[tid];
        } else {
            const int wi = atomicAdd(&nwork_s, 1);
            work_s[wi] = tid;
        }
    }

    if (kh == 0) {
        float inv[4];
#pragma unroll
        for (int r = 0; r < 4; ++r) {
            const int row = rbase + l4 * 4 + r;
            inv[r] = 1.f / (ssum[row][0] + ssum[row][1] + ssum[row][2] + ssum[row][3]);
        }
#pragma unroll
        for (int n = 0; n < 5; ++n) {
            float pc = 0.f;
#pragma unroll
            for (int r = 0; r < 4; ++r) pc += acc[n][r] * inv[r];
            pc += __shfl_xor(pc, 16);
            pc += __shfl_xor(pc, 32);
            if (l4 == 0) pacc[rs][(nf0 + n) * 16 + l15 - h * VSZ] = pc;
        }
    }
    __syncthreads();

    const int nwork = nwork_s;
    for (int it = w; it < nwork; it += 16) {
        const int row  = work_s[it];
        const int grow = row0 + row;
        const int nc   = min(cnt_s[row], 16);
        float bestv = -3.4e38f; int bestc = 0x7fffffff;
        for (int ci = 0; ci < nc; ++ci) {
            const int col = list_s[row][ci];
            float p = 0.f;
            for (int j = lane; j < KDIM; j += 64)
                p += x[(size_t)grow * KDIM + j] * W[(size_t)col * KDIM + j];
#pragma unroll
            for (int off = 32; off >= 1; off >>= 1) p += __shfl_xor(p, off);
            p += b[col];
            if (p > bestv || (p == bestv && col < bestc)) { bestv = p; bestc = col; }
        }
        if (lane == 0) code_s[row] = bestc;
    }
    __syncthreads();

    if (tid < BM) atomicAdd(&cnt_f[code_s[tid] - h * VSZ], 1.f);

    {
        const int f   = tid;                // float4 index 0..1023
        const int row = f >> 5;
        const int d4  = (f & 31) * 4;
        const int k   = code_s[row];
        const float4 v = *(const float4*)(codebook + (size_t)k * DSZ + d4);
        *(float4*)(xq + (size_t)(row0 + row) * (GSZ * DSZ) + h * DSZ + d4) = v;
    }
    __syncthreads();

    for (int i = tid; i < VSZ; i += 1024) {
        atomicAdd(&accf[h * VSZ + i], cnt_f[i]);
        atomicAdd(&accf[NCOL + h * VSZ + i], pacc[0][i] + pacc[1][i]);
    }
}

// ---------------- perplexities + constant ----------------
__global__ __launch_bounds__(640) void finalize_k(const float* __restrict__ accf,
                                                  float* __restrict__ out_scalars) {
    __shared__ float se_c[GSZ], se_p[GSZ];
    const int t = threadIdx.x;
    if (t < GSZ) { se_c[t] = 0.f; se_p[t] = 0.f; }
    __syncthreads();
    const int g = t / VSZ;
    const float hp = accf[t]        * (1.f / (float)NROWS);
    const float ap = accf[NCOL + t] * (1.f / (float)NROWS);
    float tc = hp * logf(hp + 1e-7f);
    float tp = ap * logf(ap + 1e-7f);
#pragma unroll
    for (int off = 32; off >= 1; off >>= 1) {
        tc += __shfl_xor(tc, off);
        tp += __shfl_xor(tp, off);
    }
    if ((t & 63) == 0) { atomicAdd(&se_c[g], tc); atomicAdd(&se_p[g], tp); }
    __syncthreads();
    if (t == 0) {
        out_scalars[0] = (float)NCOL;
        out_scalars[1] = expf(-se_c[0]) + expf(-se_c[1]);
        out_scalars[2] = expf(-se_p[0]) + expf(-se_p[1]);
    }
}

// ================= DIAGNOSTIC PROBES (write only to d_ws scratch) =================
// Exact K-loop wave layout / grid / occupancy of fused_vq_k; loads only, XOR-consume.

static __device__ __forceinline__ void acc4(i32x4& a, i32x4 v) {
    a[0] ^= v[0]; a[1] ^= v[1]; a[2] ^= v[2]; a[3] ^= v[3];
}

// P1: the r10 load stream verbatim (6 loads/iter, serial iterations)
__global__ __launch_bounds__(1024, 8) void probe1_k(const short* __restrict__ Xb,
                                                    const short* __restrict__ Wb,
                                                    int* __restrict__ sink) {
    const int tid = threadIdx.x, lane = tid & 63, w = tid >> 6;
    const int sb  = ((int)blockIdx.x & 7) * (NBLK / 8) + ((int)blockIdx.x >> 3);
    const int mt  = sb >> 1, h = sb & 1;
    const int kh  = w >> 3, rs = (w >> 2) & 1, cc = w & 3;
    const int hc  = h * 4 + cc;
    const short* Ap = Xb + ((size_t)(mt * 2 + rs) * NKB) * 512 + (size_t)lane * 8;
    const short* Bp = Wb + ((size_t)hc * 5) * 512 + (size_t)lane * 8;
    i32x4 a_ = (i32x4){0, 0, 0, 0};
#pragma unroll 1
    for (int kb2 = 0; kb2 < KHALF; ++kb2) {
        const int kb = kh * KHALF + kb2;
        acc4(a_, *(const i32x4*)(Ap + (size_t)kb * 512));
#pragma unroll
        for (int n = 0; n < 5; ++n)
            acc4(a_, *(const i32x4*)(Bp + (size_t)kb * (8 * 5 * 512) + n * 512));
    }
    if (lane == 0) sink[(int)blockIdx.x * 16 + w] = a_[0] ^ a_[1] ^ a_[2] ^ a_[3];
}

// P3: identical bytes, 2 k-blocks per iteration (12 loads in flight)
__global__ __launch_bounds__(1024, 8) void probe3_k(const short* __restrict__ Xb,
                                                    const short* __restrict__ Wb,
                                                    int* __restrict__ sink) {
    const int tid = threadIdx.x, lane = tid & 63, w = tid >> 6;
    const int sb  = ((int)blockIdx.x & 7) * (NBLK / 8) + ((int)blockIdx.x >> 3);
    const int mt  = sb >> 1, h = sb & 1;
    const int kh  = w >> 3, rs = (w >> 2) & 1, cc = w & 3;
    const int hc  = h * 4 + cc;
    const short* Ap = Xb + ((size_t)(mt * 2 + rs) * NKB) * 512 + (size_t)lane * 8;
    const short* Bp = Wb + ((size_t)hc * 5) * 512 + (size_t)lane * 8;
    i32x4 a_ = (i32x4){0, 0, 0, 0};
    i32x4 b_ = (i32x4){0, 0, 0, 0};
#pragma unroll 1
    for (int kb2 = 0; kb2 < KHALF; kb2 += 2) {
        const int ka = kh * KHALF + kb2;
        const int kb = ka + 1;
        i32x4 va0 = *(const i32x4*)(Ap + (size_t)ka * 512);
        i32x4 vb0 = *(const i32x4*)(Ap + (size_t)kb * 512);
        i32x4 va[5], vb[5];
#pragma unroll
        for (int n = 0; n < 5; ++n) {
            va[n] = *(const i32x4*)(Bp + (size_t)ka * (8 * 5 * 512) + n * 512);
            vb[n] = *(const i32x4*)(Bp + (size_t)kb * (8 * 5 * 512) + n * 512);
        }
        acc4(a_, va0); acc4(b_, vb0);
#pragma unroll
        for (int n = 0; n < 5; ++n) { acc4(a_, va[n]); acc4(b_, vb[n]); }
    }
    if (lane == 0)
        sink[(int)blockIdx.x * 16 + w] =
            a_[0] ^ a_[1] ^ a_[2] ^ a_[3] ^ b_[0] ^ b_[1] ^ b_[2] ^ b_[3];
}

extern "C" void kernel_launch(void* const* d_in, const int* in_sizes, int n_in,
                              void* d_out, int out_size, void* d_ws, size_t ws_size,
                              hipStream_t stream) {
    const float* x        = (const float*)d_in[0];
    const float* W        = (const float*)d_in[1];
    const float* b        = (const float*)d_in[2];
    const float* codebook = (const float*)d_in[3];
    float* out = (float*)d_out;

    short* Wb    = (short*)d_ws;                                  //   983,040 B
    short* Xb    = (short*)((char*)d_ws + 983040);                // 12,582,912 B
    float* accf  = (float*)((char*)d_ws + 983040 + 12582912);     //     5,120 B
    int*   sink1 = (int*)((char*)d_ws + 983040 + 12582912 + 5120);          // 32 KB
    int*   sink3 = (int*)((char*)d_ws + 983040 + 12582912 + 5120 + 32768);  // 32 KB

    prep_k<<<dim3(XBLKS + WBLKS), dim3(256), 0, stream>>>(x, W, Xb, Wb, accf);
    fused_vq_k<<<dim3(NBLK), dim3(1024), 0, stream>>>(Xb, Wb, x, W, b, codebook,
                                                      accf, out);
    finalize_k<<<dim3(1), dim3(640), 0, stream>>>(accf, out + XQ_TOTAL);

    // diagnostics (scratch-only; output already complete and deterministic)
    probe1_k<<<dim3(NBLK), dim3(1024), 0, stream>>>(Xb, Wb, sink1);
    probe3_k<<<dim3(NBLK), dim3(1024), 0, stream>>>(Xb, Wb, sink3);
}

// Round 12
// 50.416 us; speedup vs baseline: 1.9213x; 1.9213x over previous
//
#include <hip/hip_runtime.h>
#include <hip/hip_bf16.h>

#define NROWS 8192      // B*T
#define KDIM  768       // F_IN
#define VSZ   320       // V
#define GSZ   2         // G
#define NCOL  640       // G*V
#define DSZ   128       // D
#define BM    64        // rows per block
#define NMT   (NROWS / BM)             // 128 M-tiles
#define NBLK  (NMT * 2)                // 256 blocks (x2 group-halves) = 1/CU
#define NKB   24                       // K blocks of 32 (prep layout)
#define NK64  12                       // K steps of 64 (fused loop)
#define XQ_TOTAL (NROWS * GSZ * DSZ)   // 2097152
#define MARGIN 1.5f
#define XBLKS 3072                     // prep blocks for x
#define WBLKS 240                      // prep blocks for W

typedef __attribute__((ext_vector_type(8))) short bf16x8;
typedef __attribute__((ext_vector_type(4))) float f32x4;

static __device__ __forceinline__ short f2bf(float f) {
    union { __hip_bfloat16 h; short s; } u;
    u.h = __float2bfloat16(f);   // round-to-nearest-even
    return u.s;
}

static __device__ __forceinline__ void gload_lds16(const void* g, void* l) {
    __builtin_amdgcn_global_load_lds(
        (const __attribute__((address_space(1))) void*)g,
        (__attribute__((address_space(3))) void*)l, 16, 0, 0);
}

// ---------------- prep: pack x and W to frag-major bf16; zero accf ----------------
// Xb: frag fid = rblk*24 + kb32 (rblk 0..511 = 16-row block). 1KB/frag.
//     lane l: row = rblk*16 + (l&15), k = kb32*32 + (l>>4)*8.
// Wb: frag fid = (kb32*8 + hc)*5 + n (hc = h*4+cc): col = (hc*5+n)*16 + (l&15).
__global__ __launch_bounds__(256) void prep_k(const float* __restrict__ x,
                                              const float* __restrict__ W,
                                              short* __restrict__ Xb,
                                              short* __restrict__ Wb,
                                              float* __restrict__ accf) {
    const int bid = blockIdx.x;
    if (bid == 0) {
        for (int i = threadIdx.x; i < 2 * NCOL; i += 256) accf[i] = 0.f;
    }
    const float* src;
    short* dst;
    int id, row, k;
    if (bid < XBLKS) {
        id = bid * 256 + threadIdx.x;           // 0..786431
        const int lane = id & 63;
        const int f    = id >> 6;               // 0..12287
        const int rblk = f / NKB;
        const int kb   = f - rblk * NKB;
        row = rblk * 16 + (lane & 15);
        k   = kb * 32 + (lane >> 4) * 8;
        src = x; dst = Xb;
    } else {
        id = (bid - XBLKS) * 256 + threadIdx.x; // 0..61439
        const int lane = id & 63;
        const int f    = id >> 6;               // 0..959
        const int n    = f % 5;
        const int t2   = f / 5;
        const int hc   = t2 & 7;
        const int kb   = t2 >> 3;               // 0..23
        row = (hc * 5 + n) * 16 + (lane & 15);  // W col
        k   = kb * 32 + (lane >> 4) * 8;
        src = W; dst = Wb;
    }
    const float4 a = *(const float4*)(src + (size_t)row * KDIM + k);
    const float4 c = *(const float4*)(src + (size_t)row * KDIM + k + 4);
    bf16x8 r;
    r[0] = f2bf(a.x); r[1] = f2bf(a.y); r[2] = f2bf(a.z); r[3] = f2bf(a.w);
    r[4] = f2bf(c.x); r[5] = f2bf(c.y); r[6] = f2bf(c.z); r[7] = f2bf(c.w);
    *(bf16x8*)(dst + (size_t)id * 8) = r;
}

// Per K-step (64 k) stage: 48 frags = 8 A (f<8) + 40 B; wave w issues f = w, w+16, w+32
// (exactly 3 -> uniform vmcnt). LDS layout: frag f at byte f*1024 of the buffer.
#define STAGE(kb64, BUF) do {                                                  \
    _Pragma("unroll")                                                          \
    for (int j = 0; j < 3; ++j) {                                              \
        const int f = w + 16 * j;                                              \
        const short* src;                                                      \
        if (f < 8) {                                                           \
            src = Xb + ((size_t)(mt * 4 + (f >> 1)) * 24 + (2 * (kb64) + (f & 1))) * 512; \
        } else {                                                               \
            const int i = f - 8;                                               \
            const int kf = i / 20, rm = i % 20;                                \
            src = Wb + ((size_t)((2 * (kb64) + kf) * 8 + hc0 + rm / 5) * 5 + rm % 5) * 512; \
        }                                                                      \
        gload_lds16(src + lane * 8, (char*)(BUF) + f * 1024);                  \
    }                                                                          \
} while (0)

#define COMPUTE(BUF) do {                                                      \
    const char* _bp = (const char*)(BUF);                                      \
    const bf16x8 a0 = *(const bf16x8*)(_bp + (rs * 2 + 0) * 1024 + lane * 16); \
    const bf16x8 a1 = *(const bf16x8*)(_bp + (rs * 2 + 1) * 1024 + lane * 16); \
    bf16x8 b0_[5], b1_[5];                                                     \
    _Pragma("unroll")                                                          \
    for (int n = 0; n < 5; ++n) {                                              \
        b0_[n] = *(const bf16x8*)(_bp + 8192 + (cc * 5 + n) * 1024 + lane * 16);      \
        b1_[n] = *(const bf16x8*)(_bp + 8192 + (20 + cc * 5 + n) * 1024 + lane * 16); \
    }                                                                          \
    _Pragma("unroll")                                                          \
    for (int n = 0; n < 5; ++n)                                                \
        acc[n] = __builtin_amdgcn_mfma_f32_16x16x32_bf16(a0, b0_[n], acc[n], 0, 0, 0); \
    _Pragma("unroll")                                                          \
    for (int n = 0; n < 5; ++n)                                                \
        acc[n] = __builtin_amdgcn_mfma_f32_16x16x32_bf16(a1, b1_[n], acc[n], 0, 0, 0); \
} while (0)

// counted vmcnt: newest stage (3 loads) may stay in flight; everything older landed
#define SYNCN do {                                                             \
    asm volatile("s_waitcnt vmcnt(3)" ::: "memory");                           \
    __builtin_amdgcn_sched_barrier(0);                                         \
    __builtin_amdgcn_s_barrier();                                              \
} while (0)
#define SYNC0 do {                                                             \
    asm volatile("s_waitcnt vmcnt(0)" ::: "memory");                           \
    __builtin_amdgcn_sched_barrier(0);                                         \
    __builtin_amdgcn_s_barrier();                                              \
} while (0)

// ---------------- fused: LDS-dedup'd deep-pipelined MFMA GEMM + epilogue ----------------
// grid 256 = 128 M-tiles x 2 group-halves, 1 block/CU; 1024 threads = 16 waves (rs x cc).
// Block: rows [mt*64,+64) x cols [h*320,+320). Operands staged ONCE per block through
// LDS (3-buffer rotation, counted vmcnt, raw s_barrier) -> 151 MB total L2 traffic.
__global__ __launch_bounds__(1024, 4) void fused_vq_k(
    const short* __restrict__ Xb, const short* __restrict__ Wb,
    const float* __restrict__ x, const float* __restrict__ W,
    const float* __restrict__ b, const float* __restrict__ codebook,
    float* __restrict__ accf, float* __restrict__ xq) {

    __shared__ __align__(16) char bufs[3][48 * 1024];   // 147,456 B
    __shared__ float pacc[4][VSZ];
    __shared__ float cnt_f[VSZ];
    __shared__ float wmax[BM][4];
    __shared__ int   warg[BM][4];
    __shared__ float ssum[BM][4];
    __shared__ float rmax_s[BM];
    __shared__ int   rarg_s[BM];
    __shared__ int   cnt_s[BM];
    __shared__ int   list_s[BM][16];
    __shared__ int   code_s[BM];
    __shared__ int   work_s[BM];
    __shared__ int   nwork_s;

    const int tid   = threadIdx.x;
    const int lane  = tid & 63;
    const int w     = tid >> 6;       // wave 0..15
    const int l15   = lane & 15;
    const int l4    = lane >> 4;      // 0..3
    const int sb    = ((int)blockIdx.x & 7) * (NBLK / 8) + ((int)blockIdx.x >> 3);
    const int mt    = sb >> 1;
    const int h     = sb & 1;         // group
    const int row0  = mt * BM;
    const int rs    = w >> 2;         // row-set 0..3 (16 rows)
    const int cc    = w & 3;          // col-chunk 0..3 (80 cols)
    const int rbase = rs * 16;
    const int hc0   = h * 4;
    const int nf0   = h * 20 + cc * 5;   // first 16-col frag (global)

    for (int i = tid; i < VSZ; i += 1024) cnt_f[i] = 0.f;
    if (tid < BM) cnt_s[tid] = 0;
    if (tid == 0) nwork_s = 0;

    char* B0 = bufs[0];
    char* B1 = bufs[1];
    char* B2 = bufs[2];

    f32x4 acc[5];
#pragma unroll
    for (int n = 0; n < 5; ++n) acc[n] = (f32x4){0.f, 0.f, 0.f, 0.f};

    // prologue: stage steps 0,1; full barrier (also covers LDS inits)
    STAGE(0, B0);
    STAGE(1, B1);
    __syncthreads();

    // main loop: kb = 0..8 in static triples, 2-deep prefetch, counted vmcnt
#pragma unroll 1
    for (int t = 0; t < 3; ++t) {
        const int kb = 3 * t;
        STAGE(kb + 2, B2); COMPUTE(B0); SYNCN;
        STAGE(kb + 3, B0); COMPUTE(B1); SYNCN;
        STAGE(kb + 4, B1); COMPUTE(B2); SYNCN;
    }
    // tail: kb = 9, 10, 11
    STAGE(11, B2); COMPUTE(B0); SYNCN;
    COMPUTE(B1); SYNC0;
    COMPUTE(B2);

    // bias (zeros in this problem, kept exact)
#pragma unroll
    for (int n = 0; n < 5; ++n) {
        const float bv = b[(nf0 + n) * 16 + l15];
#pragma unroll
        for (int r = 0; r < 4; ++r) acc[n][r] += bv;
    }

    // E1: wave-local per-row max/argmax (rows rbase+l4*4+r, cols (nf0+n)*16+l15)
    float m4[4]; int a4[4];
#pragma unroll
    for (int r = 0; r < 4; ++r) { m4[r] = -3.4e38f; a4[r] = 0x7fffffff; }
#pragma unroll
    for (int n = 0; n < 5; ++n) {
        const int col = (nf0 + n) * 16 + l15;
#pragma unroll
        for (int r = 0; r < 4; ++r) {
            const float v = acc[n][r];
            if (v > m4[r]) { m4[r] = v; a4[r] = col; }
        }
    }
#pragma unroll
    for (int off = 8; off >= 1; off >>= 1)
#pragma unroll
        for (int r = 0; r < 4; ++r) {
            const float om = __shfl_xor(m4[r], off);
            const int   oa = __shfl_xor(a4[r], off);
            if (om > m4[r] || (om == m4[r] && oa < a4[r])) { m4[r] = om; a4[r] = oa; }
        }
    if (l15 == 0)
#pragma unroll
        for (int r = 0; r < 4; ++r) {
            const int row = rbase + l4 * 4 + r;
            wmax[row][cc] = m4[r];
            warg[row][cc] = a4[r];
        }
    __syncthreads();

    // E2a: combine 4 col-chunks -> row max over 320
    if (tid < BM) {
        float m = -3.4e38f; int c = 0x7fffffff;
#pragma unroll
        for (int q = 0; q < 4; ++q) {
            const float mq = wmax[tid][q];
            const int   cq = warg[tid][q];
            if (mq > m || (mq == m && cq < c)) { m = mq; c = cq; }
        }
        rmax_s[tid] = m;
        rarg_s[tid] = c;
    }
    __syncthreads();

    // E2b: candidate scan + exp + denominator partials
    float rm[4];
#pragma unroll
    for (int r = 0; r < 4; ++r) rm[r] = rmax_s[rbase + l4 * 4 + r];
    float sden[4] = {0.f, 0.f, 0.f, 0.f};
#pragma unroll
    for (int n = 0; n < 5; ++n) {
        const int col = (nf0 + n) * 16 + l15;
#pragma unroll
        for (int r = 0; r < 4; ++r) {
            const float v = acc[n][r];
            if (v > rm[r] - MARGIN) {
                const int row = rbase + l4 * 4 + r;
                const int idx = atomicAdd(&cnt_s[row], 1);
                if (idx < 16) list_s[row][idx] = col;
            }
            const float e = __expf(v - rm[r]);
            acc[n][r] = e;
            sden[r] += e;
        }
    }
#pragma unroll
    for (int off = 8; off >= 1; off >>= 1)
#pragma unroll
        for (int r = 0; r < 4; ++r) sden[r] += __shfl_xor(sden[r], off);
    if (l15 == 0)
#pragma unroll
        for (int r = 0; r < 4; ++r) ssum[rbase + l4 * 4 + r][cc] = sden[r];
    __syncthreads();

    // E3: single-candidate fast path; multi-candidate -> worklist
    if (tid < BM) {
        if (cnt_s[tid] <= 1) {
            code_s[tid] = rarg_s[tid];
        } else {
            const int wi = atomicAdd(&nwork_s, 1);
            work_s[wi] = tid;
        }
    }

    // E5: softmax column sums -> pacc[rs][v] (plain stores, disjoint (rs,cc) slots)
    float inv[4];
#pragma unroll
    for (int r = 0; r < 4; ++r) {
        const int row = rbase + l4 * 4 + r;
        inv[r] = 1.f / (ssum[row][0] + ssum[row][1] + ssum[row][2] + ssum[row][3]);
    }
#pragma unroll
    for (int n = 0; n < 5; ++n) {
        float pc = 0.f;
#pragma unroll
        for (int r = 0; r < 4; ++r) pc += acc[n][r] * inv[r];
        pc += __shfl_xor(pc, 16);
        pc += __shfl_xor(pc, 32);
        if (l4 == 0) pacc[rs][(nf0 + n) * 16 + l15 - h * VSZ] = pc;
    }
    __syncthreads();

    // E4: fp32-exact refinement, one wave per pending row
    const int nwork = nwork_s;
    for (int it = w; it < nwork; it += 16) {
        const int row  = work_s[it];
        const int grow = row0 + row;
        const int nc   = min(cnt_s[row], 16);
        float bestv = -3.4e38f; int bestc = 0x7fffffff;
        for (int ci = 0; ci < nc; ++ci) {
            const int col = list_s[row][ci];
            float p = 0.f;
            for (int j = lane; j < KDIM; j += 64)
                p += x[(size_t)grow * KDIM + j] * W[(size_t)col * KDIM + j];
#pragma unroll
            for (int off = 32; off >= 1; off >>= 1) p += __shfl_xor(p, off);
            p += b[col];
            if (p > bestv || (p == bestv && col < bestc)) { bestv = p; bestc = col; }
        }
        if (lane == 0) code_s[row] = bestc;
    }
    __syncthreads();

    // counts histogram in LDS
    if (tid < BM) atomicAdd(&cnt_f[code_s[tid] - h * VSZ], 1.f);

    // E7: gather xq for this block's 64 rows, its group's 128-dim half
#pragma unroll
    for (int u = 0; u < 2; ++u) {
        const int f   = tid + u * 1024;     // float4 index 0..2047
        const int row = f >> 5;
        const int d4  = (f & 31) * 4;
        const int k   = code_s[row];        // global col = codebook row
        const float4 v = *(const float4*)(codebook + (size_t)k * DSZ + d4);
        *(float4*)(xq + (size_t)(row0 + row) * (GSZ * DSZ) + h * DSZ + d4) = v;
    }
    __syncthreads();

    // flush block-local sums with global atomics (r3/r4 A/B: ~0 cost)
    for (int i = tid; i < VSZ; i += 1024) {
        atomicAdd(&accf[h * VSZ + i], cnt_f[i]);
        atomicAdd(&accf[NCOL + h * VSZ + i],
                  pacc[0][i] + pacc[1][i] + pacc[2][i] + pacc[3][i]);
    }
}

// ---------------- perplexities + constant ----------------
__global__ __launch_bounds__(640) void finalize_k(const float* __restrict__ accf,
                                                  float* __restrict__ out_scalars) {
    __shared__ float se_c[GSZ], se_p[GSZ];
    const int t = threadIdx.x;
    if (t < GSZ) { se_c[t] = 0.f; se_p[t] = 0.f; }
    __syncthreads();
    const int g = t / VSZ;
    const float hp = accf[t]        * (1.f / (float)NROWS);
    const float ap = accf[NCOL + t] * (1.f / (float)NROWS);
    float tc = hp * logf(hp + 1e-7f);
    float tp = ap * logf(ap + 1e-7f);
#pragma unroll
    for (int off = 32; off >= 1; off >>= 1) {
        tc += __shfl_xor(tc, off);
        tp += __shfl_xor(tp, off);
    }
    if ((t & 63) == 0) { atomicAdd(&se_c[g], tc); atomicAdd(&se_p[g], tp); }
    __syncthreads();
    if (t == 0) {
        out_scalars[0] = (float)NCOL;
        out_scalars[1] = expf(-se_c[0]) + expf(-se_c[1]);
        out_scalars[2] = expf(-se_p[0]) + expf(-se_p[1]);
    }
}

extern "C" void kernel_launch(void* const* d_in, const int* in_sizes, int n_in,
                              void* d_out, int out_size, void* d_ws, size_t ws_size,
                              hipStream_t stream) {
    const float* x        = (const float*)d_in[0];
    const float* W        = (const float*)d_in[1];
    const float* b        = (const float*)d_in[2];
    const float* codebook = (const float*)d_in[3];
    float* out = (float*)d_out;

    short* Wb   = (short*)d_ws;                                  //   983,040 B
    short* Xb   = (short*)((char*)d_ws + 983040);                // 12,582,912 B
    float* accf = (float*)((char*)d_ws + 983040 + 12582912);     //     5,120 B

    prep_k<<<dim3(XBLKS + WBLKS), dim3(256), 0, stream>>>(x, W, Xb, Wb, accf);
    fused_vq_k<<<dim3(NBLK), dim3(1024), 0, stream>>>(Xb, Wb, x, W, b, codebook,
                                                      accf, out);
    finalize_k<<<dim3(1), dim3(640), 0, stream>>>(accf, out + XQ_TOTAL);
}